// Round 5
// baseline (1260.579 us; speedup 1.0000x reference)
//
#include <hip/hip_runtime.h>
#include <math.h>

#define N_ATOMS 50000
#define N_EDGES 1600000
#define NRBF 20
#define TILE_E 32
#define N_TILES (N_EDGES / TILE_E)   // 50000 exact

typedef __attribute__((ext_vector_type(8))) short bf16x8;
typedef __attribute__((ext_vector_type(4))) float f32x4;

__device__ __forceinline__ float ssp(float v) {
    const float a = fabsf(v);
    const float e = exp2f(a * -1.4426950408889634f);
    const float l = log2f(1.0f + e);
    return fmaxf(v, 0.0f) + fmaf(l, 0.6931471805599453f, -0.6931471805599453f);
}
__device__ __forceinline__ unsigned short f2bf(float f) {   // fp32 -> bf16 bits, RNE
    unsigned int u = __float_as_uint(f);
    u += 0x7fff + ((u >> 16) & 1);
    return (unsigned short)(u >> 16);
}
__device__ __forceinline__ float bf2f(unsigned short b) {
    return __uint_as_float(((unsigned int)b) << 16);
}
// LDS-only barrier (CK idiom): drains lgkmcnt but NOT vmcnt, so register
// prefetches of global data survive across phases. Valid because all
// inter-wave traffic in the edge kernel goes through LDS.
__device__ __forceinline__ void lds_barrier() {
    __asm__ __volatile__("s_waitcnt lgkmcnt(0)\ns_barrier" ::: "memory");
}

// ---------------------------------------------------------------------------
// MFMA row-GEMM, one 32-row tile per block (unchanged from round 4).
template<bool SSP_ACT, bool BIAS>
__global__ __launch_bounds__(512) void rowgemm_mfma(
    const float* __restrict__ A, const float* __restrict__ W,
    const float* __restrict__ bias, float* __restrict__ C, int nrows)
{
    const int tid  = threadIdx.x;
    const int wave = tid >> 6, lane = tid & 63;
    const int l15  = lane & 15, quad = lane >> 4;
    const int rhalf = wave >> 2, cpair = wave & 3;
    const int r0 = rhalf * 16;
    const int rowbase = blockIdx.x * 32;
    const int arow = rowbase + r0 + l15;

    float av[4][8];
    if (arow < nrows) {
        #pragma unroll
        for (int kk = 0; kk < 4; ++kk) {
            const float4 q0 = *(const float4*)(A + (size_t)arow * 128 + kk * 32 + quad * 8);
            const float4 q1 = *(const float4*)(A + (size_t)arow * 128 + kk * 32 + quad * 8 + 4);
            av[kk][0] = q0.x; av[kk][1] = q0.y; av[kk][2] = q0.z; av[kk][3] = q0.w;
            av[kk][4] = q1.x; av[kk][5] = q1.y; av[kk][6] = q1.z; av[kk][7] = q1.w;
        }
    } else {
        #pragma unroll
        for (int kk = 0; kk < 4; ++kk)
            #pragma unroll
            for (int j = 0; j < 8; ++j) av[kk][j] = 0.0f;
    }

    bf16x8 wh[2][4], wl[2][4];
    float br[2];
    #pragma unroll
    for (int ct = 0; ct < 2; ++ct) {
        const int c = cpair * 32 + ct * 16 + l15;
        br[ct] = BIAS ? bias[c] : 0.0f;
        #pragma unroll
        for (int kk = 0; kk < 4; ++kk) {
            #pragma unroll
            for (int j = 0; j < 8; ++j) {
                const int k = kk * 32 + quad * 8 + j;
                const float v = W[k * 128 + c];
                const unsigned short hb = f2bf(v);
                wh[ct][kk][j] = (short)hb;
                wl[ct][kk][j] = (short)f2bf(v - bf2f(hb));
            }
        }
    }

    bf16x8 ah[4], al[4];
    #pragma unroll
    for (int kk = 0; kk < 4; ++kk) {
        #pragma unroll
        for (int j = 0; j < 8; ++j) {
            const unsigned short hb = f2bf(av[kk][j]);
            ah[kk][j] = (short)hb;
            al[kk][j] = (short)f2bf(av[kk][j] - bf2f(hb));
        }
    }

    #pragma unroll
    for (int ct = 0; ct < 2; ++ct) {
        f32x4 acc = {0.0f, 0.0f, 0.0f, 0.0f};
        #pragma unroll
        for (int kk = 0; kk < 4; ++kk) {
            acc = __builtin_amdgcn_mfma_f32_16x16x32_bf16(ah[kk], wh[ct][kk], acc, 0, 0, 0);
            acc = __builtin_amdgcn_mfma_f32_16x16x32_bf16(al[kk], wh[ct][kk], acc, 0, 0, 0);
            acc = __builtin_amdgcn_mfma_f32_16x16x32_bf16(ah[kk], wl[ct][kk], acc, 0, 0, 0);
        }
        const int c = cpair * 32 + ct * 16 + l15;
        #pragma unroll
        for (int r = 0; r < 4; ++r) {
            const int row = rowbase + r0 + quad * 4 + r;
            if (row < nrows) {
                float v = acc[r] + br[ct];
                if (SSP_ACT) v = ssp(v);
                C[(size_t)row * 128 + c] = v;
            }
        }
    }
}

// ---------------------------------------------------------------------------
// Fused edge kernel: lgkm-only barriers (2/tile), direct f_ij A-frag loads,
// 2-deep register pipeline for the h-gather, single-buffered sTH/sXT.
struct EdgePipe {
    float4 pa, pb;     // f_ij raw fragment halves for this pipe's tile
    float  hn[2][4];   // gathered h for this pipe's tile
    float  rc[4];      // rcut
    int    jn[4];      // idx_j for (pipe tile + 1)'s gather
    int    ii[8];      // idx_i rows (reduce role) for this pipe's tile
};

__global__ __launch_bounds__(512, 4) void edge_mfma(
    const float* __restrict__ f_ij, const float* __restrict__ rcut,
    const int* __restrict__ idx_i, const int* __restrict__ idx_j,
    const float* __restrict__ h,
    const float* __restrict__ W1, const float* __restrict__ b1,
    const float* __restrict__ W2, const float* __restrict__ b2,
    float* __restrict__ y)
{
    __shared__ unsigned short sTH[32][136];   // t tile, bf16-hi (stride pad -> uniform banks)
    __shared__ float sXT[128][33];            // xij transposed, stride 33 = conflict-free b32

    const int tid  = threadIdx.x;
    const int wave = tid >> 6, lane = tid & 63;
    const int l15  = lane & 15, quad = lane >> 4;
    const int rhalf = wave >> 2, cpair = wave & 3;
    const int r0  = rhalf * 16;
    const int c0  = cpair * 32 + l15;
    const int rr  = r0 + quad * 4;
    const int col = tid & 127, qtr = tid >> 7;

    // ---- weight fragments (hi planes only; f_ij keeps hi/lo via A) ----
    bf16x8 w1h[2];
    bf16x8 w2h[2][4];
    float b1r[2], b2r[2];
    #pragma unroll
    for (int ct = 0; ct < 2; ++ct) {
        const int c = c0 + ct * 16;
        b1r[ct] = b1[c];
        b2r[ct] = b2[c];
        #pragma unroll
        for (int j = 0; j < 8; ++j) {
            const int k = quad * 8 + j;
            w1h[ct][j] = (short)f2bf((k < NRBF) ? W1[k * 128 + c] : 0.0f);
        }
        #pragma unroll
        for (int kk = 0; kk < 4; ++kk)
            #pragma unroll
            for (int j = 0; j < 8; ++j)
                w2h[ct][kk][j] = (short)f2bf(W2[(kk * 32 + quad * 8 + j) * 128 + c]);
    }

    const int nb = gridDim.x;
    const int t0 = (int)(((long long)blockIdx.x * N_TILES) / nb);
    const int t1 = (int)(((long long)(blockIdx.x + 1) * N_TILES) / nb);
    if (t0 >= t1) return;

    int   curI = idx_i[(size_t)t0 * TILE_E];
    float accV = 0.0f;

    EdgePipe P0, P1;

    // ---- preloop: fill P0 with tile t0; P1.jn = idx_j(t0+1) ----
    {
        const int e0 = t0 * TILE_E;
        const float* rp = f_ij + (size_t)(e0 + r0 + l15) * NRBF;
        float4 za = {0,0,0,0}, zb = {0,0,0,0};
        if (quad < 2)       { za = *(const float4*)(rp + quad * 8); zb = *(const float4*)(rp + quad * 8 + 4); }
        else if (quad == 2) { za = *(const float4*)(rp + 16); }
        P0.pa = za; P0.pb = zb;
        const float4 rq = *(const float4*)(rcut + e0 + rr);
        P0.rc[0] = rq.x; P0.rc[1] = rq.y; P0.rc[2] = rq.z; P0.rc[3] = rq.w;
        const int4 j0 = *(const int4*)(idx_j + e0 + rr);
        int jt[4] = {j0.x, j0.y, j0.z, j0.w};
        #pragma unroll
        for (int ct = 0; ct < 2; ++ct)
            #pragma unroll
            for (int r = 0; r < 4; ++r)
                P0.hn[ct][r] = h[(size_t)jt[r] * 128 + c0 + ct * 16];
        const int tn = (t0 + 1 < N_TILES) ? t0 + 1 : N_TILES - 1;
        const int4 j1 = *(const int4*)(idx_j + tn * TILE_E + rr);
        P1.jn[0] = j1.x; P1.jn[1] = j1.y; P1.jn[2] = j1.z; P1.jn[3] = j1.w;
    }

    auto body = [&](int t, EdgePipe& cur, EdgePipe& nxt) {
        // ================= phase A =================
        // issue idx_i(t) load (consumed at reduce(t) in next body's phase A)
        {
            const int e0 = t * TILE_E;
            const int4 i0 = *(const int4*)(idx_i + e0 + qtr * 8);
            const int4 i1 = *(const int4*)(idx_i + e0 + qtr * 8 + 4);
            cur.ii[0] = i0.x; cur.ii[1] = i0.y; cur.ii[2] = i0.z; cur.ii[3] = i0.w;
            cur.ii[4] = i1.x; cur.ii[5] = i1.y; cur.ii[6] = i1.z; cur.ii[7] = i1.w;
        }
        // segmented reduce of tile t-1 (sXT from previous phase B)
        if (t > t0) {
            #pragma unroll
            for (int r = 0; r < 8; ++r) {
                const float v = sXT[col][qtr * 8 + r];
                const int i = nxt.ii[r];
                if (i != curI) {
                    atomicAdd(&y[(size_t)curI * 128 + col], accV);
                    curI = i; accV = v;
                } else accV += v;
            }
        }
        // layer 1: t = ssp(f_ij @ W1 + b1); A hi/lo, W1 hi
        {
            const float va[8] = {cur.pa.x, cur.pa.y, cur.pa.z, cur.pa.w,
                                 cur.pb.x, cur.pb.y, cur.pb.z, cur.pb.w};
            bf16x8 ah, al;
            #pragma unroll
            for (int j = 0; j < 8; ++j) {
                const unsigned short hb = f2bf(va[j]);
                ah[j] = (short)hb;
                al[j] = (short)f2bf(va[j] - bf2f(hb));
            }
            #pragma unroll
            for (int ct = 0; ct < 2; ++ct) {
                f32x4 d = {0.0f, 0.0f, 0.0f, 0.0f};
                d = __builtin_amdgcn_mfma_f32_16x16x32_bf16(ah, w1h[ct], d, 0, 0, 0);
                d = __builtin_amdgcn_mfma_f32_16x16x32_bf16(al, w1h[ct], d, 0, 0, 0);
                const int c = c0 + ct * 16;
                #pragma unroll
                for (int r = 0; r < 4; ++r)
                    sTH[rr + r][c] = f2bf(ssp(d[r] + b1r[ct]));
            }
        }
        lds_barrier();   // B1: sTH visible; sXT free for rewrite
        // ================= phase B =================
        // prefetch issues (survive barriers: lgkm-only sync)
        {
            // h-gather for t+1 via nxt.jn (loaded one body ago)
            #pragma unroll
            for (int ct = 0; ct < 2; ++ct)
                #pragma unroll
                for (int r = 0; r < 4; ++r)
                    nxt.hn[ct][r] = h[(size_t)nxt.jn[r] * 128 + c0 + ct * 16];
            const int ta = (t + 1 < N_TILES) ? t + 1 : N_TILES - 1;
            const int tb = (t + 2 < N_TILES) ? t + 2 : N_TILES - 1;
            const int ea = ta * TILE_E;
            // idx_j(t+2) into cur.jn (cur's slot is free now)
            const int4 j2 = *(const int4*)(idx_j + tb * TILE_E + rr);
            cur.jn[0] = j2.x; cur.jn[1] = j2.y; cur.jn[2] = j2.z; cur.jn[3] = j2.w;
            // f_ij(t+1) raw fragment
            const float* rp = f_ij + (size_t)(ea + r0 + l15) * NRBF;
            float4 za = {0,0,0,0}, zb = {0,0,0,0};
            if (quad < 2)       { za = *(const float4*)(rp + quad * 8); zb = *(const float4*)(rp + quad * 8 + 4); }
            else if (quad == 2) { za = *(const float4*)(rp + 16); }
            nxt.pa = za; nxt.pb = zb;
            // rcut(t+1)
            const float4 rq = *(const float4*)(rcut + ea + rr);
            nxt.rc[0] = rq.x; nxt.rc[1] = rq.y; nxt.rc[2] = rq.z; nxt.rc[3] = rq.w;
        }
        // layer 2: Wij = t @ W2 + b2; xij = h * Wij * rcut -> sXT (b32, stride 33)
        {
            bf16x8 ath[4];
            #pragma unroll
            for (int kk = 0; kk < 4; ++kk)
                ath[kk] = *(const bf16x8*)(&sTH[r0 + l15][kk * 32 + quad * 8]);
            #pragma unroll
            for (int ct = 0; ct < 2; ++ct) {
                f32x4 acc = {0.0f, 0.0f, 0.0f, 0.0f};
                #pragma unroll
                for (int kk = 0; kk < 4; ++kk)
                    acc = __builtin_amdgcn_mfma_f32_16x16x32_bf16(ath[kk], w2h[ct][kk], acc, 0, 0, 0);
                const int c = c0 + ct * 16;
                #pragma unroll
                for (int r = 0; r < 4; ++r) {
                    const float wij = (acc[r] + b2r[ct]) * cur.rc[r];
                    sXT[c][rr + r] = wij * cur.hn[ct][r];
                }
            }
        }
        lds_barrier();   // B2: sXT visible; sTH free for next tile
    };

    int t = t0;
    for (; t + 1 < t1; t += 2) {
        body(t,     P0, P1);
        body(t + 1, P1, P0);
    }
    const int* iiF;
    if (t < t1) { body(t, P0, P1); iiF = P0.ii; }
    else        { iiF = P1.ii; }

    // final reduce of last tile + flush
    #pragma unroll
    for (int r = 0; r < 8; ++r) {
        const float v = sXT[col][qtr * 8 + r];
        const int i = iiF[r];
        if (i != curI) {
            atomicAdd(&y[(size_t)curI * 128 + col], accV);
            curI = i; accV = v;
        } else accV += v;
    }
    atomicAdd(&y[(size_t)curI * 128 + col], accV);
}

// ---------------------------------------------------------------------------
extern "C" void kernel_launch(void* const* d_in, const int* in_sizes, int n_in,
                              void* d_out, int out_size, void* d_ws, size_t ws_size,
                              hipStream_t stream) {
    const float* x      = (const float*)d_in[0];
    const float* f_ij   = (const float*)d_in[1];
    const float* rcut   = (const float*)d_in[2];
    const int*   idx_i  = (const int*)d_in[3];
    const int*   idx_j  = (const int*)d_in[4];
    const float* W_in2f = (const float*)d_in[5];
    const float* W_f1   = (const float*)d_in[6];
    const float* b_f1   = (const float*)d_in[7];
    const float* W_f2   = (const float*)d_in[8];
    const float* b_f2   = (const float*)d_in[9];
    const float* W_o1   = (const float*)d_in[10];
    const float* b_o1   = (const float*)d_in[11];
    const float* W_o2   = (const float*)d_in[12];
    const float* b_o2   = (const float*)d_in[13];

    float* out = (float*)d_out;
    float* h   = (float*)d_ws;   // 25.6 MB; reused as z after cfconv

    hipMemsetAsync(out, 0, (size_t)N_ATOMS * 128 * sizeof(float), stream);

    const int ntiles = (N_ATOMS + 31) / 32;   // 1563
    rowgemm_mfma<false, false><<<ntiles, 512, 0, stream>>>(x, W_in2f, nullptr, h, N_ATOMS);
    edge_mfma<<<1024, 512, 0, stream>>>(f_ij, rcut, idx_i, idx_j, h,
                                        W_f1, b_f1, W_f2, b_f2, out);
    rowgemm_mfma<true, true><<<ntiles, 512, 0, stream>>>(out, W_o1, b_o1, h, N_ATOMS);
    rowgemm_mfma<false, true><<<ntiles, 512, 0, stream>>>(h, W_o2, b_o2, out, N_ATOMS);
}

// Round 6
// 1070.192 us; speedup vs baseline: 1.1779x; 1.1779x over previous
//
#include <hip/hip_runtime.h>
#include <math.h>

#define N_ATOMS 50000
#define N_EDGES 1600000
#define NRBF 20
#define TILE_E 32
#define N_TILES (N_EDGES / TILE_E)   // 50000 exact

typedef __attribute__((ext_vector_type(8))) short bf16x8;
typedef __attribute__((ext_vector_type(4))) float f32x4;

__device__ __forceinline__ float ssp(float v) {
    const float a = fabsf(v);
    const float e = exp2f(a * -1.4426950408889634f);
    const float l = log2f(1.0f + e);
    return fmaxf(v, 0.0f) + fmaf(l, 0.6931471805599453f, -0.6931471805599453f);
}
__device__ __forceinline__ unsigned short f2bf(float f) {   // fp32 -> bf16 bits, RNE
    unsigned int u = __float_as_uint(f);
    u += 0x7fff + ((u >> 16) & 1);
    return (unsigned short)(u >> 16);
}
__device__ __forceinline__ float bf2f(unsigned short b) {
    return __uint_as_float(((unsigned int)b) << 16);
}
// LDS-only barrier (CK idiom): drains lgkmcnt but NOT vmcnt, so register
// prefetches of global data survive across phases. Valid because all
// inter-wave traffic in the edge kernel goes through LDS.
__device__ __forceinline__ void lds_barrier() {
    __asm__ __volatile__("s_waitcnt lgkmcnt(0)\ns_barrier" ::: "memory");
}

// ---------------------------------------------------------------------------
// MFMA row-GEMM, one 32-row tile per block.
template<bool SSP_ACT, bool BIAS>
__global__ __launch_bounds__(512) void rowgemm_mfma(
    const float* __restrict__ A, const float* __restrict__ W,
    const float* __restrict__ bias, float* __restrict__ C, int nrows)
{
    const int tid  = threadIdx.x;
    const int wave = tid >> 6, lane = tid & 63;
    const int l15  = lane & 15, quad = lane >> 4;
    const int rhalf = wave >> 2, cpair = wave & 3;
    const int r0 = rhalf * 16;
    const int rowbase = blockIdx.x * 32;
    const int arow = rowbase + r0 + l15;

    float av[4][8];
    if (arow < nrows) {
        #pragma unroll
        for (int kk = 0; kk < 4; ++kk) {
            const float4 q0 = *(const float4*)(A + (size_t)arow * 128 + kk * 32 + quad * 8);
            const float4 q1 = *(const float4*)(A + (size_t)arow * 128 + kk * 32 + quad * 8 + 4);
            av[kk][0] = q0.x; av[kk][1] = q0.y; av[kk][2] = q0.z; av[kk][3] = q0.w;
            av[kk][4] = q1.x; av[kk][5] = q1.y; av[kk][6] = q1.z; av[kk][7] = q1.w;
        }
    } else {
        #pragma unroll
        for (int kk = 0; kk < 4; ++kk)
            #pragma unroll
            for (int j = 0; j < 8; ++j) av[kk][j] = 0.0f;
    }

    bf16x8 wh[2][4], wl[2][4];
    float br[2];
    #pragma unroll
    for (int ct = 0; ct < 2; ++ct) {
        const int c = cpair * 32 + ct * 16 + l15;
        br[ct] = BIAS ? bias[c] : 0.0f;
        #pragma unroll
        for (int kk = 0; kk < 4; ++kk) {
            #pragma unroll
            for (int j = 0; j < 8; ++j) {
                const int k = kk * 32 + quad * 8 + j;
                const float v = W[k * 128 + c];
                const unsigned short hb = f2bf(v);
                wh[ct][kk][j] = (short)hb;
                wl[ct][kk][j] = (short)f2bf(v - bf2f(hb));
            }
        }
    }

    bf16x8 ah[4], al[4];
    #pragma unroll
    for (int kk = 0; kk < 4; ++kk) {
        #pragma unroll
        for (int j = 0; j < 8; ++j) {
            const unsigned short hb = f2bf(av[kk][j]);
            ah[kk][j] = (short)hb;
            al[kk][j] = (short)f2bf(av[kk][j] - bf2f(hb));
        }
    }

    #pragma unroll
    for (int ct = 0; ct < 2; ++ct) {
        f32x4 acc = {0.0f, 0.0f, 0.0f, 0.0f};
        #pragma unroll
        for (int kk = 0; kk < 4; ++kk) {
            acc = __builtin_amdgcn_mfma_f32_16x16x32_bf16(ah[kk], wh[ct][kk], acc, 0, 0, 0);
            acc = __builtin_amdgcn_mfma_f32_16x16x32_bf16(al[kk], wh[ct][kk], acc, 0, 0, 0);
            acc = __builtin_amdgcn_mfma_f32_16x16x32_bf16(ah[kk], wl[ct][kk], acc, 0, 0, 0);
        }
        const int c = cpair * 32 + ct * 16 + l15;
        #pragma unroll
        for (int r = 0; r < 4; ++r) {
            const int row = rowbase + r0 + quad * 4 + r;
            if (row < nrows) {
                float v = acc[r] + br[ct];
                if (SSP_ACT) v = ssp(v);
                C[(size_t)row * 128 + c] = v;
            }
        }
    }
}

// ---------------------------------------------------------------------------
// Fused edge kernel: lgkm-only barriers (2/tile), direct f_ij A-frag loads,
// 2-deep register pipeline for the h-gather, single-buffered sTH/sXT.
// __launch_bounds__(512, 2): R5's (512,4) squeezed VGPRs to 64 and spilled
// the pipeline state to scratch (3.3 GB HBM traffic). 2 waves/SIMD = 128-reg
// budget = no spill.
struct EdgePipe {
    float4 pa, pb;     // f_ij raw fragment halves for this pipe's tile
    float  hn[2][4];   // gathered h for this pipe's tile
    float  rc[4];      // rcut
    int    jn[4];      // idx_j for (pipe tile + 1)'s gather
    int    ii[8];      // idx_i rows (reduce role) for this pipe's tile
};

__global__ __launch_bounds__(512, 2) void edge_mfma(
    const float* __restrict__ f_ij, const float* __restrict__ rcut,
    const int* __restrict__ idx_i, const int* __restrict__ idx_j,
    const float* __restrict__ h,
    const float* __restrict__ W1, const float* __restrict__ b1,
    const float* __restrict__ W2, const float* __restrict__ b2,
    float* __restrict__ y)
{
    __shared__ unsigned short sTH[32][136];   // t tile, bf16-hi
    __shared__ float sXT[128][33];            // xij transposed, stride 33 = conflict-free b32

    const int tid  = threadIdx.x;
    const int wave = tid >> 6, lane = tid & 63;
    const int l15  = lane & 15, quad = lane >> 4;
    const int rhalf = wave >> 2, cpair = wave & 3;
    const int r0  = rhalf * 16;
    const int c0  = cpair * 32 + l15;
    const int rr  = r0 + quad * 4;
    const int col = tid & 127, qtr = tid >> 7;

    // ---- weight fragments (hi planes only; f_ij keeps hi/lo via A) ----
    bf16x8 w1h[2];
    bf16x8 w2h[2][4];
    float b1r[2], b2r[2];
    #pragma unroll
    for (int ct = 0; ct < 2; ++ct) {
        const int c = c0 + ct * 16;
        b1r[ct] = b1[c];
        b2r[ct] = b2[c];
        #pragma unroll
        for (int j = 0; j < 8; ++j) {
            const int k = quad * 8 + j;
            w1h[ct][j] = (short)f2bf((k < NRBF) ? W1[k * 128 + c] : 0.0f);
        }
        #pragma unroll
        for (int kk = 0; kk < 4; ++kk)
            #pragma unroll
            for (int j = 0; j < 8; ++j)
                w2h[ct][kk][j] = (short)f2bf(W2[(kk * 32 + quad * 8 + j) * 128 + c]);
    }

    const int nb = gridDim.x;
    const int t0 = (int)(((long long)blockIdx.x * N_TILES) / nb);
    const int t1 = (int)(((long long)(blockIdx.x + 1) * N_TILES) / nb);
    if (t0 >= t1) return;

    int   curI = idx_i[(size_t)t0 * TILE_E];
    float accV = 0.0f;

    EdgePipe P0, P1;

    // ---- preloop: fill P0 with tile t0; P1.jn = idx_j(t0+1) ----
    {
        const int e0 = t0 * TILE_E;
        const float* rp = f_ij + (size_t)(e0 + r0 + l15) * NRBF;
        float4 za = {0,0,0,0}, zb = {0,0,0,0};
        if (quad < 2)       { za = *(const float4*)(rp + quad * 8); zb = *(const float4*)(rp + quad * 8 + 4); }
        else if (quad == 2) { za = *(const float4*)(rp + 16); }
        P0.pa = za; P0.pb = zb;
        const float4 rq = *(const float4*)(rcut + e0 + rr);
        P0.rc[0] = rq.x; P0.rc[1] = rq.y; P0.rc[2] = rq.z; P0.rc[3] = rq.w;
        const int4 j0 = *(const int4*)(idx_j + e0 + rr);
        int jt[4] = {j0.x, j0.y, j0.z, j0.w};
        #pragma unroll
        for (int ct = 0; ct < 2; ++ct)
            #pragma unroll
            for (int r = 0; r < 4; ++r)
                P0.hn[ct][r] = h[(size_t)jt[r] * 128 + c0 + ct * 16];
        const int tn = (t0 + 1 < N_TILES) ? t0 + 1 : N_TILES - 1;
        const int4 j1 = *(const int4*)(idx_j + tn * TILE_E + rr);
        P1.jn[0] = j1.x; P1.jn[1] = j1.y; P1.jn[2] = j1.z; P1.jn[3] = j1.w;
    }

    auto body = [&](int t, EdgePipe& cur, EdgePipe& nxt) {
        // ================= phase A =================
        // issue idx_i(t) load (consumed at reduce(t) in next body's phase A)
        {
            const int e0 = t * TILE_E;
            const int4 i0 = *(const int4*)(idx_i + e0 + qtr * 8);
            const int4 i1 = *(const int4*)(idx_i + e0 + qtr * 8 + 4);
            cur.ii[0] = i0.x; cur.ii[1] = i0.y; cur.ii[2] = i0.z; cur.ii[3] = i0.w;
            cur.ii[4] = i1.x; cur.ii[5] = i1.y; cur.ii[6] = i1.z; cur.ii[7] = i1.w;
        }
        // segmented reduce of tile t-1 (sXT from previous phase B)
        if (t > t0) {
            #pragma unroll
            for (int r = 0; r < 8; ++r) {
                const float v = sXT[col][qtr * 8 + r];
                const int i = nxt.ii[r];
                if (i != curI) {
                    atomicAdd(&y[(size_t)curI * 128 + col], accV);
                    curI = i; accV = v;
                } else accV += v;
            }
        }
        // layer 1: t = ssp(f_ij @ W1 + b1); A hi/lo, W1 hi
        {
            const float va[8] = {cur.pa.x, cur.pa.y, cur.pa.z, cur.pa.w,
                                 cur.pb.x, cur.pb.y, cur.pb.z, cur.pb.w};
            bf16x8 ah, al;
            #pragma unroll
            for (int j = 0; j < 8; ++j) {
                const unsigned short hb = f2bf(va[j]);
                ah[j] = (short)hb;
                al[j] = (short)f2bf(va[j] - bf2f(hb));
            }
            #pragma unroll
            for (int ct = 0; ct < 2; ++ct) {
                f32x4 d = {0.0f, 0.0f, 0.0f, 0.0f};
                d = __builtin_amdgcn_mfma_f32_16x16x32_bf16(ah, w1h[ct], d, 0, 0, 0);
                d = __builtin_amdgcn_mfma_f32_16x16x32_bf16(al, w1h[ct], d, 0, 0, 0);
                const int c = c0 + ct * 16;
                #pragma unroll
                for (int r = 0; r < 4; ++r)
                    sTH[rr + r][c] = f2bf(ssp(d[r] + b1r[ct]));
            }
        }
        lds_barrier();   // B1: sTH visible; sXT free for rewrite
        // ================= phase B =================
        // prefetch issues (survive barriers: lgkm-only sync)
        {
            // h-gather for t+1 via nxt.jn (loaded one body ago)
            #pragma unroll
            for (int ct = 0; ct < 2; ++ct)
                #pragma unroll
                for (int r = 0; r < 4; ++r)
                    nxt.hn[ct][r] = h[(size_t)nxt.jn[r] * 128 + c0 + ct * 16];
            const int ta = (t + 1 < N_TILES) ? t + 1 : N_TILES - 1;
            const int tb = (t + 2 < N_TILES) ? t + 2 : N_TILES - 1;
            const int ea = ta * TILE_E;
            // idx_j(t+2) into cur.jn (cur's slot is free now)
            const int4 j2 = *(const int4*)(idx_j + tb * TILE_E + rr);
            cur.jn[0] = j2.x; cur.jn[1] = j2.y; cur.jn[2] = j2.z; cur.jn[3] = j2.w;
            // f_ij(t+1) raw fragment
            const float* rp = f_ij + (size_t)(ea + r0 + l15) * NRBF;
            float4 za = {0,0,0,0}, zb = {0,0,0,0};
            if (quad < 2)       { za = *(const float4*)(rp + quad * 8); zb = *(const float4*)(rp + quad * 8 + 4); }
            else if (quad == 2) { za = *(const float4*)(rp + 16); }
            nxt.pa = za; nxt.pb = zb;
            // rcut(t+1)
            const float4 rq = *(const float4*)(rcut + ea + rr);
            nxt.rc[0] = rq.x; nxt.rc[1] = rq.y; nxt.rc[2] = rq.z; nxt.rc[3] = rq.w;
        }
        // layer 2: Wij = t @ W2 + b2; xij = h * Wij * rcut -> sXT (b32, stride 33)
        {
            bf16x8 ath[4];
            #pragma unroll
            for (int kk = 0; kk < 4; ++kk)
                ath[kk] = *(const bf16x8*)(&sTH[r0 + l15][kk * 32 + quad * 8]);
            #pragma unroll
            for (int ct = 0; ct < 2; ++ct) {
                f32x4 acc = {0.0f, 0.0f, 0.0f, 0.0f};
                #pragma unroll
                for (int kk = 0; kk < 4; ++kk)
                    acc = __builtin_amdgcn_mfma_f32_16x16x32_bf16(ath[kk], w2h[ct][kk], acc, 0, 0, 0);
                const int c = c0 + ct * 16;
                #pragma unroll
                for (int r = 0; r < 4; ++r) {
                    const float wij = (acc[r] + b2r[ct]) * cur.rc[r];
                    sXT[c][rr + r] = wij * cur.hn[ct][r];
                }
            }
        }
        lds_barrier();   // B2: sXT visible; sTH free for next tile
    };

    int t = t0;
    for (; t + 1 < t1; t += 2) {
        body(t,     P0, P1);
        body(t + 1, P1, P0);
    }
    const int* iiF;
    if (t < t1) { body(t, P0, P1); iiF = P0.ii; }
    else        { iiF = P1.ii; }

    // final reduce of last tile + flush
    #pragma unroll
    for (int r = 0; r < 8; ++r) {
        const float v = sXT[col][qtr * 8 + r];
        const int i = iiF[r];
        if (i != curI) {
            atomicAdd(&y[(size_t)curI * 128 + col], accV);
            curI = i; accV = v;
        } else accV += v;
    }
    atomicAdd(&y[(size_t)curI * 128 + col], accV);
}

// ---------------------------------------------------------------------------
extern "C" void kernel_launch(void* const* d_in, const int* in_sizes, int n_in,
                              void* d_out, int out_size, void* d_ws, size_t ws_size,
                              hipStream_t stream) {
    const float* x      = (const float*)d_in[0];
    const float* f_ij   = (const float*)d_in[1];
    const float* rcut   = (const float*)d_in[2];
    const int*   idx_i  = (const int*)d_in[3];
    const int*   idx_j  = (const int*)d_in[4];
    const float* W_in2f = (const float*)d_in[5];
    const float* W_f1   = (const float*)d_in[6];
    const float* b_f1   = (const float*)d_in[7];
    const float* W_f2   = (const float*)d_in[8];
    const float* b_f2   = (const float*)d_in[9];
    const float* W_o1   = (const float*)d_in[10];
    const float* b_o1   = (const float*)d_in[11];
    const float* W_o2   = (const float*)d_in[12];
    const float* b_o2   = (const float*)d_in[13];

    float* out = (float*)d_out;
    float* h   = (float*)d_ws;   // 25.6 MB; reused as z after cfconv

    hipMemsetAsync(out, 0, (size_t)N_ATOMS * 128 * sizeof(float), stream);

    const int ntiles = (N_ATOMS + 31) / 32;   // 1563
    rowgemm_mfma<false, false><<<ntiles, 512, 0, stream>>>(x, W_in2f, nullptr, h, N_ATOMS);
    edge_mfma<<<1024, 512, 0, stream>>>(f_ij, rcut, idx_i, idx_j, h,
                                        W_f1, b_f1, W_f2, b_f2, out);
    rowgemm_mfma<true, true><<<ntiles, 512, 0, stream>>>(out, W_o1, b_o1, h, N_ATOMS);
    rowgemm_mfma<false, true><<<ntiles, 512, 0, stream>>>(h, W_o2, b_o2, out, N_ATOMS);
}

// Round 7
// 695.155 us; speedup vs baseline: 1.8134x; 1.5395x over previous
//
#include <hip/hip_runtime.h>
#include <math.h>

#define N_ATOMS 50000
#define N_EDGES 1600000
#define NRBF 20
#define TILE_E 32
#define N_TILES (N_EDGES / TILE_E)   // 50000 exact

typedef __attribute__((ext_vector_type(8))) short bf16x8;
typedef __attribute__((ext_vector_type(4))) float f32x4;

__device__ __forceinline__ float ssp(float v) {
    const float a = fabsf(v);
    const float e = exp2f(a * -1.4426950408889634f);
    const float l = log2f(1.0f + e);
    return fmaxf(v, 0.0f) + fmaf(l, 0.6931471805599453f, -0.6931471805599453f);
}
__device__ __forceinline__ unsigned short f2bf(float f) {   // fp32 -> bf16 bits, RNE
    unsigned int u = __float_as_uint(f);
    u += 0x7fff + ((u >> 16) & 1);
    return (unsigned short)(u >> 16);
}
__device__ __forceinline__ float bf2f(unsigned short b) {
    return __uint_as_float(((unsigned int)b) << 16);
}
// LDS-only barrier (CK idiom): drains lgkmcnt but NOT vmcnt, so register
// prefetches of global data survive across phases. Valid because all
// inter-wave traffic in the edge kernel goes through LDS.
__device__ __forceinline__ void lds_barrier() {
    __asm__ __volatile__("s_waitcnt lgkmcnt(0)\ns_barrier" ::: "memory");
}

// ---------------------------------------------------------------------------
// MFMA row-GEMM, grid-stride (several tiles per block): W loaded+converted
// once per block; next A tile prefetched before computing the current one.
template<bool SSP_ACT, bool BIAS>
__global__ __launch_bounds__(512) void rowgemm_mfma(
    const float* __restrict__ A, const float* __restrict__ W,
    const float* __restrict__ bias, float* __restrict__ C, int nrows)
{
    const int tid  = threadIdx.x;
    const int wave = tid >> 6, lane = tid & 63;
    const int l15  = lane & 15, quad = lane >> 4;
    const int rhalf = wave >> 2, cpair = wave & 3;
    const int r0 = rhalf * 16;
    const int ntiles = (nrows + 31) >> 5;
    const int stride = gridDim.x;

    int t = blockIdx.x;
    if (t >= ntiles) return;

    // ---- issue first A tile load (overlaps W conversion) ----
    float av[4][8];
    {
        const int arow0 = t * 32 + r0 + l15;
        const int arow = (arow0 < nrows) ? arow0 : (nrows - 1);
        #pragma unroll
        for (int kk = 0; kk < 4; ++kk) {
            const float4 q0 = *(const float4*)(A + (size_t)arow * 128 + kk * 32 + quad * 8);
            const float4 q1 = *(const float4*)(A + (size_t)arow * 128 + kk * 32 + quad * 8 + 4);
            av[kk][0] = q0.x; av[kk][1] = q0.y; av[kk][2] = q0.z; av[kk][3] = q0.w;
            av[kk][4] = q1.x; av[kk][5] = q1.y; av[kk][6] = q1.z; av[kk][7] = q1.w;
        }
    }

    // ---- W fragments (hi/lo), once per block ----
    bf16x8 wh[2][4], wl[2][4];
    float br[2];
    #pragma unroll
    for (int ct = 0; ct < 2; ++ct) {
        const int c = cpair * 32 + ct * 16 + l15;
        br[ct] = BIAS ? bias[c] : 0.0f;
        #pragma unroll
        for (int kk = 0; kk < 4; ++kk) {
            #pragma unroll
            for (int j = 0; j < 8; ++j) {
                const int k = kk * 32 + quad * 8 + j;
                const float v = W[k * 128 + c];
                const unsigned short hb = f2bf(v);
                wh[ct][kk][j] = (short)hb;
                wl[ct][kk][j] = (short)f2bf(v - bf2f(hb));
            }
        }
    }

    while (true) {
        const int tn = t + stride;
        const bool more = (tn < ntiles);
        // ---- prefetch next A tile ----
        float avn[4][8];
        if (more) {
            const int arow0 = tn * 32 + r0 + l15;
            const int arow = (arow0 < nrows) ? arow0 : (nrows - 1);
            #pragma unroll
            for (int kk = 0; kk < 4; ++kk) {
                const float4 q0 = *(const float4*)(A + (size_t)arow * 128 + kk * 32 + quad * 8);
                const float4 q1 = *(const float4*)(A + (size_t)arow * 128 + kk * 32 + quad * 8 + 4);
                avn[kk][0] = q0.x; avn[kk][1] = q0.y; avn[kk][2] = q0.z; avn[kk][3] = q0.w;
                avn[kk][4] = q1.x; avn[kk][5] = q1.y; avn[kk][6] = q1.z; avn[kk][7] = q1.w;
            }
        }
        // ---- compute tile t ----
        bf16x8 ah[4], al[4];
        #pragma unroll
        for (int kk = 0; kk < 4; ++kk) {
            #pragma unroll
            for (int j = 0; j < 8; ++j) {
                const unsigned short hb = f2bf(av[kk][j]);
                ah[kk][j] = (short)hb;
                al[kk][j] = (short)f2bf(av[kk][j] - bf2f(hb));
            }
        }
        #pragma unroll
        for (int ct = 0; ct < 2; ++ct) {
            f32x4 acc = {0.0f, 0.0f, 0.0f, 0.0f};
            #pragma unroll
            for (int kk = 0; kk < 4; ++kk) {
                acc = __builtin_amdgcn_mfma_f32_16x16x32_bf16(ah[kk], wh[ct][kk], acc, 0, 0, 0);
                acc = __builtin_amdgcn_mfma_f32_16x16x32_bf16(al[kk], wh[ct][kk], acc, 0, 0, 0);
                acc = __builtin_amdgcn_mfma_f32_16x16x32_bf16(ah[kk], wl[ct][kk], acc, 0, 0, 0);
            }
            const int c = cpair * 32 + ct * 16 + l15;
            #pragma unroll
            for (int r = 0; r < 4; ++r) {
                const int row = t * 32 + r0 + quad * 4 + r;
                if (row < nrows) {
                    float v = acc[r] + br[ct];
                    if (SSP_ACT) v = ssp(v);
                    C[(size_t)row * 128 + c] = v;
                }
            }
        }
        if (!more) break;
        #pragma unroll
        for (int kk = 0; kk < 4; ++kk)
            #pragma unroll
            for (int j = 0; j < 8; ++j) av[kk][j] = avn[kk][j];
        t = tn;
    }
}

// ---------------------------------------------------------------------------
// Fused edge kernel: lgkm-only barriers (2/tile), direct f_ij A-frag loads,
// register pipeline held in PLAIN LOCALS rotated by assignment (no structs,
// no address-taken arrays — R5/R6's EdgePipe + iiF pointer forced the whole
// pipeline into scratch: 0.5-2.7 GB of spill traffic).
__global__ __launch_bounds__(512, 2) void edge_mfma(
    const float* __restrict__ f_ij, const float* __restrict__ rcut,
    const int* __restrict__ idx_i, const int* __restrict__ idx_j,
    const float* __restrict__ h,
    const float* __restrict__ W1, const float* __restrict__ b1,
    const float* __restrict__ W2, const float* __restrict__ b2,
    float* __restrict__ y)
{
    __shared__ unsigned short sTH[32][136];   // t tile, bf16-hi
    __shared__ float sXT[128][33];            // xij transposed, stride 33 = conflict-free b32

    const int tid  = threadIdx.x;
    const int wave = tid >> 6, lane = tid & 63;
    const int l15  = lane & 15, quad = lane >> 4;
    const int rhalf = wave >> 2, cpair = wave & 3;
    const int r0  = rhalf * 16;
    const int c0  = cpair * 32 + l15;
    const int rr  = r0 + quad * 4;
    const int col = tid & 127, qtr = tid >> 7;

    // ---- weight fragments (hi planes; f_ij keeps hi/lo via A operand) ----
    bf16x8 w1h[2];
    bf16x8 w2h[2][4];
    float b1r[2], b2r[2];
    #pragma unroll
    for (int ct = 0; ct < 2; ++ct) {
        const int c = c0 + ct * 16;
        b1r[ct] = b1[c];
        b2r[ct] = b2[c];
        #pragma unroll
        for (int j = 0; j < 8; ++j) {
            const int k = quad * 8 + j;
            w1h[ct][j] = (short)f2bf((k < NRBF) ? W1[k * 128 + c] : 0.0f);
        }
        #pragma unroll
        for (int kk = 0; kk < 4; ++kk)
            #pragma unroll
            for (int j = 0; j < 8; ++j)
                w2h[ct][kk][j] = (short)f2bf(W2[(kk * 32 + quad * 8 + j) * 128 + c]);
    }

    const int nb = gridDim.x;
    const int t0 = (int)(((long long)blockIdx.x * N_TILES) / nb);
    const int t1 = (int)(((long long)(blockIdx.x + 1) * N_TILES) / nb);
    if (t0 >= t1) return;

    int   curI = idx_i[(size_t)t0 * TILE_E];
    float accV = 0.0f;

    // ---- pipeline state (plain locals) ----
    float4 apa, apb;        // f_ij fragment, tile t
    float  arc0, arc1, arc2, arc3;          // rcut, tile t
    float  ahn[2][4];       // h gather, tile t
    int    jn0, jn1, jn2v, jn3;             // idx_j, tile t+1

    // ---- preload tile t0 ----
    {
        const int e0 = t0 * TILE_E;
        const float* rp = f_ij + (size_t)(e0 + r0 + l15) * NRBF;
        float4 za = {0,0,0,0}, zb = {0,0,0,0};
        if (quad < 2)       { za = *(const float4*)(rp + quad * 8); zb = *(const float4*)(rp + quad * 8 + 4); }
        else if (quad == 2) { za = *(const float4*)(rp + 16); }
        apa = za; apb = zb;
        const float4 rq = *(const float4*)(rcut + e0 + rr);
        arc0 = rq.x; arc1 = rq.y; arc2 = rq.z; arc3 = rq.w;
        const int4 j0 = *(const int4*)(idx_j + e0 + rr);
        ahn[0][0] = h[(size_t)j0.x * 128 + c0];
        ahn[0][1] = h[(size_t)j0.y * 128 + c0];
        ahn[0][2] = h[(size_t)j0.z * 128 + c0];
        ahn[0][3] = h[(size_t)j0.w * 128 + c0];
        ahn[1][0] = h[(size_t)j0.x * 128 + c0 + 16];
        ahn[1][1] = h[(size_t)j0.y * 128 + c0 + 16];
        ahn[1][2] = h[(size_t)j0.z * 128 + c0 + 16];
        ahn[1][3] = h[(size_t)j0.w * 128 + c0 + 16];
        const int tn = (t0 + 1 < N_TILES) ? t0 + 1 : N_TILES - 1;
        const int4 j1 = *(const int4*)(idx_j + tn * TILE_E + rr);
        jn0 = j1.x; jn1 = j1.y; jn2v = j1.z; jn3 = j1.w;
    }

    for (int t = t0; t < t1; ++t) {
        const int e0 = t * TILE_E;
        const int ta = (t + 1 < N_TILES) ? t + 1 : N_TILES - 1;
        const int tb = (t + 2 < N_TILES) ? t + 2 : N_TILES - 1;

        // ================= prefetch issue (top of iteration) =================
        int ii[8];
        {
            const int4 i0 = *(const int4*)(idx_i + e0 + qtr * 8);
            const int4 i1 = *(const int4*)(idx_i + e0 + qtr * 8 + 4);
            ii[0] = i0.x; ii[1] = i0.y; ii[2] = i0.z; ii[3] = i0.w;
            ii[4] = i1.x; ii[5] = i1.y; ii[6] = i1.z; ii[7] = i1.w;
        }
        float4 npa = {0,0,0,0}, npb = {0,0,0,0};
        {
            const float* rp = f_ij + (size_t)(ta * TILE_E + r0 + l15) * NRBF;
            if (quad < 2)       { npa = *(const float4*)(rp + quad * 8); npb = *(const float4*)(rp + quad * 8 + 4); }
            else if (quad == 2) { npa = *(const float4*)(rp + 16); }
        }
        float nrc0, nrc1, nrc2, nrc3;
        {
            const float4 rq = *(const float4*)(rcut + ta * TILE_E + rr);
            nrc0 = rq.x; nrc1 = rq.y; nrc2 = rq.z; nrc3 = rq.w;
        }
        int j20, j21, j22, j23;
        {
            const int4 jq = *(const int4*)(idx_j + tb * TILE_E + rr);
            j20 = jq.x; j21 = jq.y; j22 = jq.z; j23 = jq.w;
        }
        float nhn[2][4];   // h gather for tile t+1 (jn loaded last iteration)
        nhn[0][0] = h[(size_t)jn0 * 128 + c0];
        nhn[0][1] = h[(size_t)jn1 * 128 + c0];
        nhn[0][2] = h[(size_t)jn2v * 128 + c0];
        nhn[0][3] = h[(size_t)jn3 * 128 + c0];
        nhn[1][0] = h[(size_t)jn0 * 128 + c0 + 16];
        nhn[1][1] = h[(size_t)jn1 * 128 + c0 + 16];
        nhn[1][2] = h[(size_t)jn2v * 128 + c0 + 16];
        nhn[1][3] = h[(size_t)jn3 * 128 + c0 + 16];

        // ================= layer 1: t = ssp(f_ij @ W1 + b1) =================
        {
            const float va[8] = {apa.x, apa.y, apa.z, apa.w, apb.x, apb.y, apb.z, apb.w};
            bf16x8 ah, al;
            #pragma unroll
            for (int j = 0; j < 8; ++j) {
                const unsigned short hb = f2bf(va[j]);
                ah[j] = (short)hb;
                al[j] = (short)f2bf(va[j] - bf2f(hb));
            }
            #pragma unroll
            for (int ct = 0; ct < 2; ++ct) {
                f32x4 d = {0.0f, 0.0f, 0.0f, 0.0f};
                d = __builtin_amdgcn_mfma_f32_16x16x32_bf16(ah, w1h[ct], d, 0, 0, 0);
                d = __builtin_amdgcn_mfma_f32_16x16x32_bf16(al, w1h[ct], d, 0, 0, 0);
                const int c = c0 + ct * 16;
                #pragma unroll
                for (int r = 0; r < 4; ++r)
                    sTH[rr + r][c] = f2bf(ssp(d[r] + b1r[ct]));
            }
        }
        lds_barrier();   // B1: sTH visible; sXT free (prev reads done pre-B1)

        // ================= layer 2: xij -> sXT =================
        {
            bf16x8 ath[4];
            #pragma unroll
            for (int kk = 0; kk < 4; ++kk)
                ath[kk] = *(const bf16x8*)(&sTH[r0 + l15][kk * 32 + quad * 8]);
            const float arcv[4] = {arc0, arc1, arc2, arc3};
            #pragma unroll
            for (int ct = 0; ct < 2; ++ct) {
                f32x4 acc = {0.0f, 0.0f, 0.0f, 0.0f};
                #pragma unroll
                for (int kk = 0; kk < 4; ++kk)
                    acc = __builtin_amdgcn_mfma_f32_16x16x32_bf16(ath[kk], w2h[ct][kk], acc, 0, 0, 0);
                const int c = c0 + ct * 16;
                #pragma unroll
                for (int r = 0; r < 4; ++r) {
                    const float wij = (acc[r] + b2r[ct]) * arcv[r];
                    sXT[c][rr + r] = wij * ahn[ct][r];
                }
            }
        }
        lds_barrier();   // B2: sXT visible; sTH free for next tile

        // ================= segmented reduce (sorted idx_i) =================
        #pragma unroll
        for (int r = 0; r < 8; ++r) {
            const float v = sXT[col][qtr * 8 + r];
            const int i = ii[r];
            if (i != curI) {
                atomicAdd(&y[(size_t)curI * 128 + col], accV);
                curI = i; accV = v;
            } else accV += v;
        }

        // ================= rotate pipeline state =================
        apa = npa; apb = npb;
        arc0 = nrc0; arc1 = nrc1; arc2 = nrc2; arc3 = nrc3;
        #pragma unroll
        for (int ct = 0; ct < 2; ++ct)
            #pragma unroll
            for (int r = 0; r < 4; ++r) ahn[ct][r] = nhn[ct][r];
        jn0 = j20; jn1 = j21; jn2v = j22; jn3 = j23;
    }
    atomicAdd(&y[(size_t)curI * 128 + col], accV);
}

// ---------------------------------------------------------------------------
extern "C" void kernel_launch(void* const* d_in, const int* in_sizes, int n_in,
                              void* d_out, int out_size, void* d_ws, size_t ws_size,
                              hipStream_t stream) {
    const float* x      = (const float*)d_in[0];
    const float* f_ij   = (const float*)d_in[1];
    const float* rcut   = (const float*)d_in[2];
    const int*   idx_i  = (const int*)d_in[3];
    const int*   idx_j  = (const int*)d_in[4];
    const float* W_in2f = (const float*)d_in[5];
    const float* W_f1   = (const float*)d_in[6];
    const float* b_f1   = (const float*)d_in[7];
    const float* W_f2   = (const float*)d_in[8];
    const float* b_f2   = (const float*)d_in[9];
    const float* W_o1   = (const float*)d_in[10];
    const float* b_o1   = (const float*)d_in[11];
    const float* W_o2   = (const float*)d_in[12];
    const float* b_o2   = (const float*)d_in[13];

    float* out = (float*)d_out;
    float* h   = (float*)d_ws;   // 25.6 MB; reused as z after cfconv

    hipMemsetAsync(out, 0, (size_t)N_ATOMS * 128 * sizeof(float), stream);

    rowgemm_mfma<false, false><<<512, 512, 0, stream>>>(x, W_in2f, nullptr, h, N_ATOMS);
    edge_mfma<<<1024, 512, 0, stream>>>(f_ij, rcut, idx_i, idx_j, h,
                                        W_f1, b_f1, W_f2, b_f2, out);
    rowgemm_mfma<true, true><<<512, 512, 0, stream>>>(out, W_o1, b_o1, h, N_ATOMS);
    rowgemm_mfma<false, true><<<512, 512, 0, stream>>>(h, W_o2, b_o2, out, N_ATOMS);
}